// Round 3
// baseline (2308.914 us; speedup 1.0000x reference)
//
#include <hip/hip_runtime.h>
#include <hip/hip_bf16.h>

#define TT 2048
#define BB 256
#define II 64
#define HH 128
#define GG 512   // 4*H
#define NHH 512
#define OO 64

#define OSTRIDE 516   // halves/row: dword-stride 258 %32 = 2 -> b64 reads at conflict floor

typedef _Float16 h2    __attribute__((ext_vector_type(2)));
typedef _Float16 half4 __attribute__((ext_vector_type(4)));
typedef _Float16 half8 __attribute__((ext_vector_type(8)));
typedef float f32x4    __attribute__((ext_vector_type(4)));

__device__ __forceinline__ float sigm(float x) {
    return __builtin_amdgcn_rcpf(1.f + __expf(-x));
}
__device__ __forceinline__ float tanh_f(float x) {
    float e = __expf(-2.f * fabsf(x));
    float t = (1.f - e) * __builtin_amdgcn_rcpf(1.f + e);
    return copysignf(t, x);
}
// LDS-only barrier: waits lgkmcnt(0) but NOT vmcnt -> no HBM-store drain per step
__device__ __forceinline__ void sync_lds() {
    __builtin_amdgcn_s_waitcnt(0xC07F);
    __builtin_amdgcn_s_barrier();
}
// v_dot2_f32_f16: 2 f16 MACs into f32 accumulator, full-rate VALU
__device__ __forceinline__ float dot2(h2 a, h2 b, float c) {
#if __has_builtin(__builtin_amdgcn_fdot2)
    return __builtin_amdgcn_fdot2(a, b, c, false);
#else
    return c + (float)a[0] * (float)b[0] + (float)a[1] * (float)b[1];
#endif
}
__device__ __forceinline__ unsigned short h2us(_Float16 h) {
    union { _Float16 h; unsigned short u; } v; v.h = h; return v.u;
}

// ---------- prep: f16 conversions for the head weights ----------
__global__ void prep_kernel(const float* __restrict__ W1, const float* __restrict__ W2,
                            _Float16* __restrict__ W1h, _Float16* __restrict__ W2h)
{
    int tid = blockIdx.x * blockDim.x + threadIdx.x;
    int n = gridDim.x * blockDim.x;
    for (int i = tid; i < NHH * HH; i += n) W1h[i] = (_Float16)W1[i];
    for (int i = tid; i < OO * NHH; i += n) W2h[i] = (_Float16)W2[i];
}

// ---------- LSTM scan: 256 blocks x 1 batch row, VALU dot2 recurrence ----------
// Thread tid owns output n = g*128 + c where c = tid>>2 (h-col), g = tid&3 (gate i/f/g/o).
// Per-lane: W_hh row (64 h2 VGPRs) + W_ih row (32 h2 VGPRs) held permanently.
// Per step: h_t (128 f16) + x_t (64 f16) broadcast-read from LDS (same-addr, conflict-free),
// 96 v_dot2_f32_f16 per lane (true-FLOP, no MFMA M-waste), per-gate nonlinearity in
// ONE exp+rcp (tanh via 2*sigm(2x)-1), quad allgather via 4 ds_swizzle broadcasts,
// c-state in registers (replicated across the quad), single barrier per step.
__global__ __launch_bounds__(512, 2) void lstm_scan8(
    const float* __restrict__ x,
    const float* __restrict__ W_ih, const float* __restrict__ W_hh,
    const float* __restrict__ b_ih, const float* __restrict__ b_hh,
    unsigned short* __restrict__ hs, float* __restrict__ out_tail)
{
    __shared__ __align__(16) _Float16 hbuf[2][HH];
    __shared__ __align__(16) _Float16 xbuf[2][II];

    const int tid = threadIdx.x;
    const int b   = blockIdx.x;        // one batch row per block
    const int cc  = tid >> 2;          // h column 0..127
    const int g   = tid & 3;           // gate: 0=i 1=f 2=g 3=o (PyTorch order)
    const int n   = g * HH + cc;       // gate pre-act index = W row

    if (tid < 2 * HH) ((_Float16*)hbuf)[tid] = (_Float16)0.f;   // h_{-1} = 0, both buffers

    // permanent per-lane weights, packed f16 pairs (full unroll -> registers)
    h2 Wh[64], Wi[32];
    #pragma unroll
    for (int k = 0; k < 64; ++k) {
        float2 f = *(const float2*)&W_hh[(size_t)n * HH + 2 * k];
        h2 p = {(_Float16)f.x, (_Float16)f.y};
        Wh[k] = p;
    }
    #pragma unroll
    for (int k = 0; k < 32; ++k) {
        float2 f = *(const float2*)&W_ih[(size_t)n * II + 2 * k];
        h2 p = {(_Float16)f.x, (_Float16)f.y};
        Wi[k] = p;
    }
    const float bias = b_ih[n] + b_hh[n];

    // x staging: wave 0 (tid<64) stages x[t][b][tid] as f16; 2-step register prefetch,
    // t-loop unrolled x2 so xa/xb alternate (load->use gap = 2 steps ~ HBM latency)
    float xa = 0.f, xb_r = 0.f;
    if (tid < II) {
        xbuf[0][tid] = (_Float16)x[(size_t)b * II + tid];              // x_0
        xa   = x[((size_t)1 * BB + b) * II + tid];                     // x_1
        xb_r = x[((size_t)2 * BB + b) * II + tid];                     // x_2
    }
    const float* xp = x + ((size_t)3 * BB + b) * II + tid;

    float cst = 0.f, hlast = 0.f;
    unsigned short* hp = hs + (size_t)b * HH + cc;   // g==0 lanes write

    __syncthreads();   // full sync once: LDS init visible

    auto step = [&](int t, int par, float& xreg) {
        const _Float16* hb  = hbuf[par];
        const _Float16* xbp = xbuf[par];

        float a0 = bias, a1 = 0.f, a2 = 0.f, a3 = 0.f;
        #pragma unroll
        for (int k = 0; k < 16; ++k) {            // h part: K=128
            union { half8 v; h2 p[4]; } u;
            u.v = *(const half8*)&hb[k * 8];      // broadcast ds_read_b128
            a0 = dot2(u.p[0], Wh[k * 4 + 0], a0);
            a1 = dot2(u.p[1], Wh[k * 4 + 1], a1);
            a2 = dot2(u.p[2], Wh[k * 4 + 2], a2);
            a3 = dot2(u.p[3], Wh[k * 4 + 3], a3);
        }
        #pragma unroll
        for (int k = 0; k < 8; ++k) {             // x part: K=64
            union { half8 v; h2 p[4]; } u;
            u.v = *(const half8*)&xbp[k * 8];
            a0 = dot2(u.p[0], Wi[k * 4 + 0], a0);
            a1 = dot2(u.p[1], Wi[k * 4 + 1], a1);
            a2 = dot2(u.p[2], Wi[k * 4 + 2], a2);
            a3 = dot2(u.p[3], Wi[k * 4 + 3], a3);
        }

        // stage x_{t+1} into the other buffer, refill xreg with x_{t+3}
        if (tid < II) {
            xbuf[par ^ 1][tid] = (_Float16)xreg;
            xreg = (t + 3 < TT) ? *xp : 0.f;
            xp += BB * II;
        }

        float pre = (a0 + a1) + (a2 + a3);
        // per-gate nonlinearity in one exp+rcp: tanh(x) = 2*sigm(2x) - 1
        float u2 = (g == 2) ? 2.f * pre : pre;
        float s  = sigm(u2);
        float a  = (g == 2) ? 2.f * s - 1.f : s;

        // quad allgather: broadcast lane j of each 4-lane quad (single ds_swizzle each)
        float ai = __uint_as_float(__builtin_amdgcn_ds_swizzle(__float_as_uint(a), 0x8000 | 0x00));
        float af = __uint_as_float(__builtin_amdgcn_ds_swizzle(__float_as_uint(a), 0x8000 | 0x55));
        float ag = __uint_as_float(__builtin_amdgcn_ds_swizzle(__float_as_uint(a), 0x8000 | 0xAA));
        float ao = __uint_as_float(__builtin_amdgcn_ds_swizzle(__float_as_uint(a), 0x8000 | 0xFF));

        float cn = af * cst + ai * ag;            // c state replicated across the quad
        cst = cn;
        float hn = ao * tanh_f(cn);
        hlast = hn;
        if (g == 0) {
            _Float16 hf = (_Float16)hn;
            hbuf[par ^ 1][cc] = hf;
            *hp = h2us(hf);
        }
        hp += (size_t)BB * HH;
        sync_lds();   // h_{t+1} (and x_{t+1}) visible; single barrier per step
    };

    for (int t = 0; t < TT; t += 2) {
        step(t, 0, xa);
        step(t + 1, 1, xb_r);
    }

    if (g == 0) {
        out_tail[(size_t)b * HH + cc] = hlast;
        out_tail[(size_t)BB * HH + (size_t)b * HH + cc] = cst;
    }
}

// ---------- fused head MLP: 64 rows/block, fully hoisted A/B frags, f16 MFMA ----------
__global__ __launch_bounds__(512, 2) void head_mfma3(
    const unsigned short* __restrict__ hs,
    const _Float16* __restrict__ W1h, const float* __restrict__ b1,
    const _Float16* __restrict__ W2h, const float* __restrict__ b2,
    float* __restrict__ out)
{
    __shared__ _Float16 o1[64 * OSTRIDE];   // 66 KB -> 2 blocks/CU

    const int tid = threadIdx.x, wv = tid >> 6, lane = tid & 63;
    const int lrow = lane & 15, q = lane >> 4;
    const size_t rows0 = (size_t)blockIdx.x * 64;
    const _Float16* hsf = (const _Float16*)hs;

    // GEMM1: wave wv owns cols [wv*64, wv*64+64); all 4 M-tiles.
    short8_dummy: ;
    half8 B1[4][4];   // [nt][kt]
    #pragma unroll
    for (int nt = 0; nt < 4; ++nt)
        #pragma unroll
        for (int kt = 0; kt < 4; ++kt)
            B1[nt][kt] = *(const half8*)&W1h[(wv * 64 + nt * 16 + lrow) * HH + kt * 32 + q * 8];
    half8 A1[4][4];   // [mt][kt]
    #pragma unroll
    for (int mt = 0; mt < 4; ++mt)
        #pragma unroll
        for (int kt = 0; kt < 4; ++kt)
            A1[mt][kt] = *(const half8*)(hsf + (rows0 + mt * 16 + lrow) * HH + kt * 32 + q * 8);

    #pragma unroll
    for (int mt = 0; mt < 4; ++mt) {
        f32x4 C1[4];
        #pragma unroll
        for (int nt = 0; nt < 4; ++nt) {
            float bv = b1[wv * 64 + nt * 16 + lrow];
            f32x4 ci = {bv, bv, bv, bv};
            C1[nt] = ci;
        }
        #pragma unroll
        for (int kt = 0; kt < 4; ++kt)
            #pragma unroll
            for (int nt = 0; nt < 4; ++nt)
                C1[nt] = __builtin_amdgcn_mfma_f32_16x16x32_f16(A1[mt][kt], B1[nt][kt], C1[nt], 0, 0, 0);
        #pragma unroll
        for (int nt = 0; nt < 4; ++nt)
            #pragma unroll
            for (int reg = 0; reg < 4; ++reg) {
                float v = C1[nt][reg];
                v = v > 0.f ? v : 0.f;
                o1[(mt * 16 + q * 4 + reg) * OSTRIDE + wv * 64 + nt * 16 + lrow] = (_Float16)v;
            }
    }
    __syncthreads();

    // GEMM2: wave -> (mt2 = wv>>1 of 4 M-tiles, nh pair = (wv&1)*2 of 4 N-tiles)
    const int mt2 = wv >> 1;
    const int nh0 = (wv & 1) * 2;
    f32x4 C2a[2], C2b[2];
    #pragma unroll
    for (int j = 0; j < 2; ++j) {
        float bv = b2[(nh0 + j) * 16 + lrow];
        f32x4 ci = {bv, bv, bv, bv};
        C2a[j] = ci;
        f32x4 z = {0.f, 0.f, 0.f, 0.f};
        C2b[j] = z;
    }
    #pragma unroll
    for (int kt = 0; kt < 16; ++kt) {
        int off = (mt2 * 16 + lrow) * OSTRIDE + kt * 32 + q * 8;
        union { half8 v; half4 h[2]; } u;
        u.h[0] = *(const half4*)&o1[off];
        u.h[1] = *(const half4*)&o1[off + 4];
        #pragma unroll
        for (int j = 0; j < 2; ++j) {
            half8 Bfr = *(const half8*)&W2h[((nh0 + j) * 16 + lrow) * NHH + kt * 32 + q * 8];
            if (kt & 1) C2b[j] = __builtin_amdgcn_mfma_f32_16x16x32_f16(u.v, Bfr, C2b[j], 0, 0, 0);
            else        C2a[j] = __builtin_amdgcn_mfma_f32_16x16x32_f16(u.v, Bfr, C2a[j], 0, 0, 0);
        }
    }
    #pragma unroll
    for (int j = 0; j < 2; ++j)
        #pragma unroll
        for (int reg = 0; reg < 4; ++reg)
            out[(rows0 + mt2 * 16 + q * 4 + reg) * OO + (nh0 + j) * 16 + lrow] = C2a[j][reg] + C2b[j][reg];
}

extern "C" void kernel_launch(void* const* d_in, const int* in_sizes, int n_in,
                              void* d_out, int out_size, void* d_ws, size_t ws_size,
                              hipStream_t stream)
{
    const float* x    = (const float*)d_in[0];
    const float* W_ih = (const float*)d_in[1];
    const float* W_hh = (const float*)d_in[2];
    const float* b_ih = (const float*)d_in[3];
    const float* b_hh = (const float*)d_in[4];
    const float* W1   = (const float*)d_in[5];
    const float* b1   = (const float*)d_in[6];
    const float* W2   = (const float*)d_in[7];
    const float* b2   = (const float*)d_in[8];
    float* out = (float*)d_out;

    char* ws = (char*)d_ws;
    _Float16* W1h = (_Float16*)(ws + 0);                   // 131072
    _Float16* W2h = (_Float16*)(ws + 131072);              // 65536
    unsigned short* hs = (unsigned short*)(ws + 196608);   // 134217728 (f16 h history)

    prep_kernel<<<64, 256, 0, stream>>>(W1, W2, W1h, W2h);

    float* tail = out + (size_t)TT * BB * OO;
    lstm_scan8<<<BB, 512, 0, stream>>>(x, W_ih, W_hh, b_ih, b_hh, hs, tail);

    head_mfma3<<<(TT * BB) / 64, 512, 0, stream>>>(hs, W1h, b1, W2h, b2, out);
}

// Round 4
// 1551.139 us; speedup vs baseline: 1.4885x; 1.4885x over previous
//
#include <hip/hip_runtime.h>
#include <hip/hip_bf16.h>

#define TT 2048
#define BB 256
#define II 64
#define HH 128
#define GG 512   // 4*H
#define NHH 512
#define OO 64

#define OSTRIDE 520    // halves/row: 1040 B = 16B-aligned; dwords 260 %32=4 -> 2-way floor
#define W2STRIDE 520
#define XSTRIDE 72     // halves/row: 144 B = 16B-aligned; dwords 36 %32=4 -> 2-way floor
#define GSTRIDE 516    // halves/row for xg window (b16 accesses only)

typedef _Float16 h2    __attribute__((ext_vector_type(2)));
typedef _Float16 half4 __attribute__((ext_vector_type(4)));
typedef _Float16 half8 __attribute__((ext_vector_type(8)));
typedef float f32x4    __attribute__((ext_vector_type(4)));

__device__ __forceinline__ float sigm(float x) {
    return __builtin_amdgcn_rcpf(1.f + __expf(-x));
}
__device__ __forceinline__ float tanh_f(float x) {
    float e = __expf(-2.f * fabsf(x));
    float t = (1.f - e) * __builtin_amdgcn_rcpf(1.f + e);
    return copysignf(t, x);
}
// LDS-only barrier: waits lgkmcnt(0) but NOT vmcnt -> no HBM-store drain per step
__device__ __forceinline__ void sync_lds() {
    __builtin_amdgcn_s_waitcnt(0xC07F);
    __builtin_amdgcn_s_barrier();
}

// ---------- prep: f16 conversions for the head weights ----------
__global__ void prep_kernel(const float* __restrict__ W1, const float* __restrict__ W2,
                            _Float16* __restrict__ W1h, _Float16* __restrict__ W2h)
{
    int tid = blockIdx.x * blockDim.x + threadIdx.x;
    int n = gridDim.x * blockDim.x;
    for (int i = tid; i < NHH * HH; i += n) W1h[i] = (_Float16)W1[i];
    for (int i = tid; i < OO * NHH; i += n) W2h[i] = (_Float16)W2[i];
}

// ---------- LSTM scan: 256 blocks x 1 batch row, 8 waves, gate-interleaved MFMA ----------
// Recurrence K=128 (h only): 16 MFMA/wave/step. The x-projection xg = x@W_ih^T + bias is
// computed IN-KERNEL per 16-step window as an M=16 MFMA GEMM (all 16 M-rows = timesteps are
// real): 8 MFMA/wave per WINDOW (amortized 0.5/step) instead of 8/step. Window results live
// in a double-buffered LDS buffer xgw[2][16][GSTRIDE]; each step seeds its gate MFMA C-init
// from 4 ds_read_u16. x for window w+1 is staged at phase 0 (from regs prefetched a window
// ahead); the w+1 window GEMM runs at phase 8. Single barrier per step.
__global__ __launch_bounds__(512, 2) void lstm_scan9(
    const float* __restrict__ x,
    const float* __restrict__ W_ih, const float* __restrict__ W_hh,
    const float* __restrict__ b_ih, const float* __restrict__ b_hh,
    _Float16* __restrict__ hs, float* __restrict__ out_tail)
{
    __shared__ __align__(16) _Float16 hbuf[2][HH];
    __shared__ __align__(16) _Float16 xstage[2][16 * XSTRIDE];
    __shared__ __align__(16) _Float16 xgw[2][16 * GSTRIDE];

    const int tid  = threadIdx.x;
    const int wv   = tid >> 6;            // 8 waves
    const int lane = tid & 63;
    const int lrow = lane & 15;
    const int q    = lane >> 4;
    const int b    = blockIdx.x;          // one batch row per block
    const int col  = wv * 16 + lrow;      // this lane's h-column (lanes<16 only)

    if (tid < 2 * HH) ((_Float16*)hbuf)[tid] = (_Float16)0.f;   // h_{-1} = 0, both buffers

    // B-frags: gate g, cols [wv*16,+16). Bh = W_hh (K=128, 4 kt), Bx = W_ih (K=64, 2 kt).
    half8 Bh[4][4], Bx[4][2];
    float biasv[4];
    int colg[4];
    #pragma unroll
    for (int g = 0; g < 4; ++g) {
        int n = g * HH + col;
        colg[g] = n;
        biasv[g] = b_ih[n] + b_hh[n];
        #pragma unroll
        for (int kt = 0; kt < 4; ++kt) {
            const float* p = W_hh + (size_t)n * HH + kt * 32 + q * 8;
            float4 f0 = *(const float4*)p;
            float4 f1 = *(const float4*)(p + 4);
            half8 bb = {(_Float16)f0.x, (_Float16)f0.y, (_Float16)f0.z, (_Float16)f0.w,
                        (_Float16)f1.x, (_Float16)f1.y, (_Float16)f1.z, (_Float16)f1.w};
            Bh[g][kt] = bb;
        }
        #pragma unroll
        for (int kt = 0; kt < 2; ++kt) {
            const float* p = W_ih + (size_t)n * II + kt * 32 + q * 8;
            float4 f0 = *(const float4*)p;
            float4 f1 = *(const float4*)(p + 4);
            half8 bb = {(_Float16)f0.x, (_Float16)f0.y, (_Float16)f0.z, (_Float16)f0.w,
                        (_Float16)f1.x, (_Float16)f1.y, (_Float16)f1.z, (_Float16)f1.w};
            Bx[g][kt] = bb;
        }
    }

    // prologue: stage x window 0 (t = 0..15); 1024 elems / 512 threads
    #pragma unroll
    for (int j = 0; j < 2; ++j) {
        int e = tid + j * 512, r = e >> 6, c2 = e & 63;
        xstage[0][r * XSTRIDE + c2] = (_Float16)x[((size_t)r * BB + b) * II + c2];
    }
    __syncthreads();
    // window-0 xg GEMM: D[m=step][n=gatecol] = x @ W_ih^T + bias
    {
        half8 Ax0 = *(const half8*)&xstage[0][lrow * XSTRIDE + q * 8];
        half8 Ax1 = *(const half8*)&xstage[0][lrow * XSTRIDE + 32 + q * 8];
        #pragma unroll
        for (int g = 0; g < 4; ++g) {
            f32x4 Cg = {biasv[g], biasv[g], biasv[g], biasv[g]};
            Cg = __builtin_amdgcn_mfma_f32_16x16x32_f16(Ax0, Bx[g][0], Cg, 0, 0, 0);
            Cg = __builtin_amdgcn_mfma_f32_16x16x32_f16(Ax1, Bx[g][1], Cg, 0, 0, 0);
            #pragma unroll
            for (int reg = 0; reg < 4; ++reg)
                xgw[0][(q * 4 + reg) * GSTRIDE + colg[g]] = (_Float16)Cg[reg];
        }
    }
    // register prefetch of x window 1 (2 floats/thread, consumed at phase 0 of window 0)
    float xr0, xr1;
    {
        int r0 = tid >> 6, c0 = tid & 63;
        int r1 = (tid + 512) >> 6, c1 = tid & 63;
        xr0 = x[((size_t)(16 + r0) * BB + b) * II + c0];
        xr1 = x[((size_t)(16 + r1) * BB + b) * II + c1];
    }
    __syncthreads();   // xgw[0] visible

    float cst = 0.f, hlast = 0.f;
    _Float16* hp = hs + (size_t)b * HH + col;

    for (int t = 0; t < TT; ++t) {
        const int par   = t & 1;
        const int wp    = (t >> 4) & 1;
        const int phase = t & 15;
        const _Float16* hb = hbuf[par];

        // A-frags: h broadcast (16 lanes per address -> conflict-free)
        half8 Af[4];
        #pragma unroll
        for (int kt = 0; kt < 4; ++kt)
            Af[kt] = *(const half8*)&hb[kt * 32 + q * 8];

        // xg seed for this step (only lane q==0 / reg0 value is consumed downstream)
        float seed[4];
        #pragma unroll
        for (int g = 0; g < 4; ++g)
            seed[g] = (float)xgw[wp][phase * GSTRIDE + colg[g]];

        // window machinery (wave-uniform branches)
        if (phase == 0 && t + 16 < TT) {
            int r0 = tid >> 6, c0 = tid & 63;
            int r1 = (tid + 512) >> 6, c1 = tid & 63;
            xstage[wp ^ 1][r0 * XSTRIDE + c0] = (_Float16)xr0;
            xstage[wp ^ 1][r1 * XSTRIDE + c1] = (_Float16)xr1;
            if (t + 32 < TT) {
                xr0 = x[((size_t)(t + 32 + r0) * BB + b) * II + c0];
                xr1 = x[((size_t)(t + 32 + r1) * BB + b) * II + c1];
            }
        }
        if (phase == 8 && t + 8 < TT) {   // compute xg for window w+1
            const _Float16* xs = xstage[wp ^ 1];
            half8 Ax0 = *(const half8*)&xs[lrow * XSTRIDE + q * 8];
            half8 Ax1 = *(const half8*)&xs[lrow * XSTRIDE + 32 + q * 8];
            #pragma unroll
            for (int g = 0; g < 4; ++g) {
                f32x4 Cg = {biasv[g], biasv[g], biasv[g], biasv[g]};
                Cg = __builtin_amdgcn_mfma_f32_16x16x32_f16(Ax0, Bx[g][0], Cg, 0, 0, 0);
                Cg = __builtin_amdgcn_mfma_f32_16x16x32_f16(Ax1, Bx[g][1], Cg, 0, 0, 0);
                #pragma unroll
                for (int reg = 0; reg < 4; ++reg)
                    xgw[wp ^ 1][(q * 4 + reg) * GSTRIDE + colg[g]] = (_Float16)Cg[reg];
            }
        }

        // recurrence: 16 MFMA (4 gates x 4 kt), split accumulators
        f32x4 Ca[4], Cb[4];
        #pragma unroll
        for (int g = 0; g < 4; ++g) {
            f32x4 ci = {seed[g], 0.f, 0.f, 0.f};
            Ca[g] = ci;
            f32x4 z = {0.f, 0.f, 0.f, 0.f};
            Cb[g] = z;
        }
        #pragma unroll
        for (int kt = 0; kt < 2; ++kt)
            #pragma unroll
            for (int g = 0; g < 4; ++g)
                Ca[g] = __builtin_amdgcn_mfma_f32_16x16x32_f16(Af[kt], Bh[g][kt], Ca[g], 0, 0, 0);
        #pragma unroll
        for (int kt = 2; kt < 4; ++kt)
            #pragma unroll
            for (int g = 0; g < 4; ++g)
                Cb[g] = __builtin_amdgcn_mfma_f32_16x16x32_f16(Af[kt], Bh[g][kt], Cb[g], 0, 0, 0);

        // in-register activations: lane l<16 holds {i,f,g,o} of col wv*16+l at reg 0
        if (lane < 16) {
            float gi = Ca[0][0] + Cb[0][0];
            float gf = Ca[1][0] + Cb[1][0];
            float gg = Ca[2][0] + Cb[2][0];
            float go = Ca[3][0] + Cb[3][0];
            cst = sigm(gf) * cst + sigm(gi) * tanh_f(gg);
            float hn = sigm(go) * tanh_f(cst);
            hlast = hn;
            _Float16 hf = (_Float16)hn;
            hbuf[par ^ 1][col] = hf;
            *hp = hf;
        }
        hp += (size_t)BB * HH;
        sync_lds();   // h_{t+1} / staged x / xg window visible; single barrier per step
    }

    if (lane < 16) {
        out_tail[(size_t)b * HH + col] = hlast;
        out_tail[(size_t)BB * HH + (size_t)b * HH + col] = cst;
    }
}

// ---------- persistent fused head MLP: 256 blocks x 32 tiles of 64 rows ----------
// W1 slice hoisted in registers ONCE per block (wave owns 64 cols), W2 staged in LDS ONCE.
// hs A-frags prefetched one mt-tile ahead (HBM latency hidden under MFMA). LDS-only barriers.
__global__ __launch_bounds__(512, 2) void head_mfma4(
    const _Float16* __restrict__ hs,
    const _Float16* __restrict__ W1h, const float* __restrict__ b1,
    const _Float16* __restrict__ W2h, const float* __restrict__ b2,
    float* __restrict__ out)
{
    __shared__ __align__(16) _Float16 o1[64 * OSTRIDE];     // 66560 B
    __shared__ __align__(16) _Float16 w2s[64 * W2STRIDE];   // 66560 B (total 133 KB, 1 blk/CU)

    const int tid = threadIdx.x, wv = tid >> 6, lane = tid & 63;
    const int lrow = lane & 15, q = lane >> 4;

    // stage W2 (64x512) into padded LDS once
    for (int i = tid; i < OO * NHH; i += 512)
        w2s[(i >> 9) * W2STRIDE + (i & 511)] = W2h[i];

    // hoist W1 slice: wave owns cols [wv*64, +64)
    half8 B1[4][4];
    float bias1[4];
    #pragma unroll
    for (int nt = 0; nt < 4; ++nt) {
        bias1[nt] = b1[wv * 64 + nt * 16 + lrow];
        #pragma unroll
        for (int kt = 0; kt < 4; ++kt)
            B1[nt][kt] = *(const half8*)&W1h[(wv * 64 + nt * 16 + lrow) * HH + kt * 32 + q * 8];
    }
    const int mt2 = wv >> 1;          // GEMM2: 4 M-tiles x 2 N-pairs over 8 waves
    const int nh0 = (wv & 1) * 2;
    float bias2[2] = {b2[nh0 * 16 + lrow], b2[(nh0 + 1) * 16 + lrow]};

    const size_t row_base = (size_t)blockIdx.x * (32 * 64);

    // A prefetch for (tile 0, mt 0)
    half8 An[4];
    #pragma unroll
    for (int kt = 0; kt < 4; ++kt)
        An[kt] = *(const half8*)(hs + (row_base + lrow) * HH + kt * 32 + q * 8);

    __syncthreads();   // w2s ready

    for (int tile = 0; tile < 32; ++tile) {
        const size_t rows0 = row_base + (size_t)tile * 64;

        // GEMM1: 4 M-tiles, A streamed with 1-tile prefetch, B resident
        #pragma unroll
        for (int mt = 0; mt < 4; ++mt) {
            half8 Ac[4];
            #pragma unroll
            for (int kt = 0; kt < 4; ++kt) Ac[kt] = An[kt];
            if (!(tile == 31 && mt == 3)) {
                size_t nrow = rows0 + (size_t)(mt + 1) * 16;   // next mt / next tile's mt0
                #pragma unroll
                for (int kt = 0; kt < 4; ++kt)
                    An[kt] = *(const half8*)(hs + (nrow + lrow) * HH + kt * 32 + q * 8);
            }
            f32x4 C1[4];
            #pragma unroll
            for (int nt = 0; nt < 4; ++nt) {
                f32x4 ci = {bias1[nt], bias1[nt], bias1[nt], bias1[nt]};
                C1[nt] = ci;
            }
            #pragma unroll
            for (int kt = 0; kt < 4; ++kt)
                #pragma unroll
                for (int nt = 0; nt < 4; ++nt)
                    C1[nt] = __builtin_amdgcn_mfma_f32_16x16x32_f16(Ac[kt], B1[nt][kt], C1[nt], 0, 0, 0);
            #pragma unroll
            for (int nt = 0; nt < 4; ++nt)
                #pragma unroll
                for (int reg = 0; reg < 4; ++reg) {
                    float v = C1[nt][reg];
                    v = v > 0.f ? v : 0.f;
                    o1[(mt * 16 + q * 4 + reg) * OSTRIDE + wv * 64 + nt * 16 + lrow] = (_Float16)v;
                }
        }
        sync_lds();   // o1 complete

        // GEMM2: all operands in LDS
        f32x4 C2a[2], C2b[2];
        #pragma unroll
        for (int j = 0; j < 2; ++j) {
            f32x4 ci = {bias2[j], bias2[j], bias2[j], bias2[j]};
            C2a[j] = ci;
            f32x4 z = {0.f, 0.f, 0.f, 0.f};
            C2b[j] = z;
        }
        #pragma unroll
        for (int kt = 0; kt < 16; ++kt) {
            half8 ua = *(const half8*)&o1[(mt2 * 16 + lrow) * OSTRIDE + kt * 32 + q * 8];
            #pragma unroll
            for (int j = 0; j < 2; ++j) {
                half8 ub = *(const half8*)&w2s[((nh0 + j) * 16 + lrow) * W2STRIDE + kt * 32 + q * 8];
                if (kt & 1) C2b[j] = __builtin_amdgcn_mfma_f32_16x16x32_f16(ua, ub, C2b[j], 0, 0, 0);
                else        C2a[j] = __builtin_amdgcn_mfma_f32_16x16x32_f16(ua, ub, C2a[j], 0, 0, 0);
            }
        }
        #pragma unroll
        for (int j = 0; j < 2; ++j)
            #pragma unroll
            for (int reg = 0; reg < 4; ++reg)
                out[(rows0 + mt2 * 16 + q * 4 + reg) * OO + (nh0 + j) * 16 + lrow] = C2a[j][reg] + C2b[j][reg];
        sync_lds();   // o1 free for next tile
    }
}

extern "C" void kernel_launch(void* const* d_in, const int* in_sizes, int n_in,
                              void* d_out, int out_size, void* d_ws, size_t ws_size,
                              hipStream_t stream)
{
    const float* x    = (const float*)d_in[0];
    const float* W_ih = (const float*)d_in[1];
    const float* W_hh = (const float*)d_in[2];
    const float* b_ih = (const float*)d_in[3];
    const float* b_hh = (const float*)d_in[4];
    const float* W1   = (const float*)d_in[5];
    const float* b1   = (const float*)d_in[6];
    const float* W2   = (const float*)d_in[7];
    const float* b2   = (const float*)d_in[8];
    float* out = (float*)d_out;

    char* ws = (char*)d_ws;
    _Float16* W1h = (_Float16*)(ws + 0);             // 131072
    _Float16* W2h = (_Float16*)(ws + 131072);        // 65536
    _Float16* hs  = (_Float16*)(ws + 196608);        // 134217728 (f16 h history)

    prep_kernel<<<64, 256, 0, stream>>>(W1, W2, W1h, W2h);

    float* tail = out + (size_t)TT * BB * OO;
    lstm_scan9<<<BB, 512, 0, stream>>>(x, W_ih, W_hh, b_ih, b_hh, hs, tail);

    head_mfma4<<<BB, 512, 0, stream>>>(hs, W1h, b1, W2h, b2, out);
}

// Round 5
// 1361.519 us; speedup vs baseline: 1.6958x; 1.1393x over previous
//
#include <hip/hip_runtime.h>
#include <hip/hip_bf16.h>

#define TT 2048
#define BB 256
#define II 64
#define HH 128
#define GG 512   // 4*H
#define NHH 512
#define OO 64

#define OSTRIDE 520    // halves/row: 1040 B = 16B-aligned; dwords 260 %32=4 -> 2-way floor
#define W2STRIDE 520
#define XSTRIDE 72     // halves/row: 144 B = 16B-aligned; dwords 36 %32=4 -> 2-way floor
#define GSTRIDE 516    // halves/row for xg window (b16 accesses only)

typedef _Float16 h2    __attribute__((ext_vector_type(2)));
typedef _Float16 half4 __attribute__((ext_vector_type(4)));
typedef _Float16 half8 __attribute__((ext_vector_type(8)));
typedef float f32x4    __attribute__((ext_vector_type(4)));

__device__ __forceinline__ float sigm(float x) {
    return __builtin_amdgcn_rcpf(1.f + __expf(-x));
}
__device__ __forceinline__ float tanh_f(float x) {
    float e = __expf(-2.f * fabsf(x));
    float t = (1.f - e) * __builtin_amdgcn_rcpf(1.f + e);
    return copysignf(t, x);
}
// LDS-only barrier: waits lgkmcnt(0) but NOT vmcnt -> no HBM-store drain per step
__device__ __forceinline__ void sync_lds() {
    __builtin_amdgcn_s_waitcnt(0xC07F);
    __builtin_amdgcn_s_barrier();
}

// ---------- prep: f16 conversions for the head weights ----------
__global__ void prep_kernel(const float* __restrict__ W1, const float* __restrict__ W2,
                            _Float16* __restrict__ W1h, _Float16* __restrict__ W2h)
{
    int tid = blockIdx.x * blockDim.x + threadIdx.x;
    int n = gridDim.x * blockDim.x;
    for (int i = tid; i < NHH * HH; i += n) W1h[i] = (_Float16)W1[i];
    for (int i = tid; i < OO * NHH; i += n) W2h[i] = (_Float16)W2[i];
}

// ---------- LSTM scan: 256 blocks x 1 batch row, 8 waves, gate-interleaved MFMA ----------
// Same algorithm as scan9 (K=128 recurrence + in-kernel 16-step xg window GEMM) but the
// 16-step window is FULLY UNROLLED: phase/parity/offsets all compile-time, window
// machinery branches static, single accumulator per gate (16 init movs, no Ca+Cb adds),
// and the per-step xg seed is SOFTWARE-PIPELINED (step t prefetches t+1's 4 ds_read_u16,
// consumed next step) so seed latency is off the critical path.
__global__ __launch_bounds__(512, 2) void lstm_scan10(
    const float* __restrict__ x,
    const float* __restrict__ W_ih, const float* __restrict__ W_hh,
    const float* __restrict__ b_ih, const float* __restrict__ b_hh,
    _Float16* __restrict__ hs, float* __restrict__ out_tail)
{
    __shared__ __align__(16) _Float16 hbuf[2][HH];
    __shared__ __align__(16) _Float16 xstage[2][16 * XSTRIDE];
    __shared__ __align__(16) _Float16 xgw[2][16 * GSTRIDE];

    const int tid  = threadIdx.x;
    const int wv   = tid >> 6;            // 8 waves
    const int lane = tid & 63;
    const int lrow = lane & 15;
    const int q    = lane >> 4;
    const int b    = blockIdx.x;          // one batch row per block
    const int col  = wv * 16 + lrow;      // this lane's h-column (lanes<16 only)

    if (tid < 2 * HH) ((_Float16*)hbuf)[tid] = (_Float16)0.f;   // h_{-1} = 0, both buffers

    // B-frags: gate g, cols [wv*16,+16). Bh = W_hh (K=128, 4 kt), Bx = W_ih (K=64, 2 kt).
    half8 Bh[4][4], Bx[4][2];
    float biasv[4];
    int colg[4];
    #pragma unroll
    for (int g = 0; g < 4; ++g) {
        int n = g * HH + col;
        colg[g] = n;
        biasv[g] = b_ih[n] + b_hh[n];
        #pragma unroll
        for (int kt = 0; kt < 4; ++kt) {
            const float* p = W_hh + (size_t)n * HH + kt * 32 + q * 8;
            float4 f0 = *(const float4*)p;
            float4 f1 = *(const float4*)(p + 4);
            half8 bb = {(_Float16)f0.x, (_Float16)f0.y, (_Float16)f0.z, (_Float16)f0.w,
                        (_Float16)f1.x, (_Float16)f1.y, (_Float16)f1.z, (_Float16)f1.w};
            Bh[g][kt] = bb;
        }
        #pragma unroll
        for (int kt = 0; kt < 2; ++kt) {
            const float* p = W_ih + (size_t)n * II + kt * 32 + q * 8;
            float4 f0 = *(const float4*)p;
            float4 f1 = *(const float4*)(p + 4);
            half8 bb = {(_Float16)f0.x, (_Float16)f0.y, (_Float16)f0.z, (_Float16)f0.w,
                        (_Float16)f1.x, (_Float16)f1.y, (_Float16)f1.z, (_Float16)f1.w};
            Bx[g][kt] = bb;
        }
    }

    // prologue: stage x window 0 (t = 0..15); 1024 elems / 512 threads
    #pragma unroll
    for (int j = 0; j < 2; ++j) {
        int e = tid + j * 512, r = e >> 6, c2 = e & 63;
        xstage[0][r * XSTRIDE + c2] = (_Float16)x[((size_t)r * BB + b) * II + c2];
    }
    __syncthreads();
    // window-0 xg GEMM: D[m=step][n=gatecol] = x @ W_ih^T + bias
    {
        half8 Ax0 = *(const half8*)&xstage[0][lrow * XSTRIDE + q * 8];
        half8 Ax1 = *(const half8*)&xstage[0][lrow * XSTRIDE + 32 + q * 8];
        #pragma unroll
        for (int g = 0; g < 4; ++g) {
            f32x4 Cg = {biasv[g], biasv[g], biasv[g], biasv[g]};
            Cg = __builtin_amdgcn_mfma_f32_16x16x32_f16(Ax0, Bx[g][0], Cg, 0, 0, 0);
            Cg = __builtin_amdgcn_mfma_f32_16x16x32_f16(Ax1, Bx[g][1], Cg, 0, 0, 0);
            #pragma unroll
            for (int reg = 0; reg < 4; ++reg)
                xgw[0][(q * 4 + reg) * GSTRIDE + colg[g]] = (_Float16)Cg[reg];
        }
    }
    // register prefetch of x window 1 (2 floats/thread, consumed at phase 0 of window 0)
    float xr0, xr1;
    const int xr_r0 = tid >> 6, xr_c = tid & 63;
    const int xr_r1 = (tid + 512) >> 6;
    xr0 = x[((size_t)(16 + xr_r0) * BB + b) * II + xr_c];
    xr1 = x[((size_t)(16 + xr_r1) * BB + b) * II + xr_c];
    __syncthreads();   // xgw[0] visible

    // seed pipeline: sc = seeds for the step about to execute
    _Float16 sc[4];
    #pragma unroll
    for (int g = 0; g < 4; ++g) sc[g] = xgw[0][colg[g]];

    float cst = 0.f;
    _Float16* hp = hs + (size_t)b * HH + col;

    for (int w = 0; w < TT / 16; ++w) {
        const int wp = w & 1;
        const _Float16* xgw_cur = xgw[wp];
        const _Float16* xgw_nxt = xgw[wp ^ 1];

        #pragma unroll
        for (int phase = 0; phase < 16; ++phase) {
            const int par = phase & 1;                  // compile-time
            const _Float16* hb = hbuf[par];

            // A-frags: h broadcast (16 lanes per address -> conflict-free), static offsets
            half8 Af[4];
            #pragma unroll
            for (int kt = 0; kt < 4; ++kt)
                Af[kt] = *(const half8*)&hb[kt * 32 + q * 8];

            // prefetch seeds for the NEXT step (phase+1; phase 15 -> next window's phase 0,
            // written at this window's phase 8 -> already visible). Consumed next phase.
            _Float16 sn[4];
            {
                const _Float16* sp = (phase == 15) ? xgw_nxt : (xgw_cur + (phase + 1) * GSTRIDE);
                #pragma unroll
                for (int g = 0; g < 4; ++g) sn[g] = sp[colg[g]];
            }

            // window machinery (static phases, wave-uniform tests)
            if (phase == 0) {
                int t = w * 16;
                if (t + 16 < TT) {
                    xstage[wp ^ 1][xr_r0 * XSTRIDE + xr_c] = (_Float16)xr0;
                    xstage[wp ^ 1][xr_r1 * XSTRIDE + xr_c] = (_Float16)xr1;
                    if (t + 32 < TT) {
                        xr0 = x[((size_t)(t + 32 + xr_r0) * BB + b) * II + xr_c];
                        xr1 = x[((size_t)(t + 32 + xr_r1) * BB + b) * II + xr_c];
                    }
                }
            }
            if (phase == 8) {
                if (w * 16 + 16 < TT) {   // compute xg for window w+1
                    const _Float16* xs = xstage[wp ^ 1];
                    half8 Ax0 = *(const half8*)&xs[lrow * XSTRIDE + q * 8];
                    half8 Ax1 = *(const half8*)&xs[lrow * XSTRIDE + 32 + q * 8];
                    #pragma unroll
                    for (int g = 0; g < 4; ++g) {
                        f32x4 Cg = {biasv[g], biasv[g], biasv[g], biasv[g]};
                        Cg = __builtin_amdgcn_mfma_f32_16x16x32_f16(Ax0, Bx[g][0], Cg, 0, 0, 0);
                        Cg = __builtin_amdgcn_mfma_f32_16x16x32_f16(Ax1, Bx[g][1], Cg, 0, 0, 0);
                        #pragma unroll
                        for (int reg = 0; reg < 4; ++reg)
                            xgw[wp ^ 1][(q * 4 + reg) * GSTRIDE + colg[g]] = (_Float16)Cg[reg];
                    }
                }
            }

            // recurrence: 16 MFMA (4 gates x 4 kt), single accumulator per gate
            f32x4 C[4];
            #pragma unroll
            for (int g = 0; g < 4; ++g) {
                float s = (float)sc[g];
                f32x4 ci = {s, s, s, s};
                C[g] = ci;
            }
            #pragma unroll
            for (int kt = 0; kt < 4; ++kt)
                #pragma unroll
                for (int g = 0; g < 4; ++g)
                    C[g] = __builtin_amdgcn_mfma_f32_16x16x32_f16(Af[kt], Bh[g][kt], C[g], 0, 0, 0);

            // in-register activations: lane l<16 holds {i,f,g,o} of col wv*16+l at reg 0
            if (lane < 16) {
                float gi = C[0][0];
                float gf = C[1][0];
                float gg = C[2][0];
                float go = C[3][0];
                cst = sigm(gf) * cst + sigm(gi) * tanh_f(gg);
                float hn = sigm(go) * tanh_f(cst);
                _Float16 hf = (_Float16)hn;
                hbuf[par ^ 1][col] = hf;
                *hp = hf;
            }
            hp += (size_t)BB * HH;
            #pragma unroll
            for (int g = 0; g < 4; ++g) sc[g] = sn[g];
            sync_lds();   // h_{t+1} / staged x / xg window visible; single barrier per step
        }
    }

    if (lane < 16) {
        out_tail[(size_t)b * HH + col] = (float)hbuf[0][col];   // last write was par^1 = 0
        out_tail[(size_t)BB * HH + (size_t)b * HH + col] = cst;
    }
}

// ---------- persistent fused head MLP: 256 blocks x 32 tiles of 64 rows ----------
// W1 slice hoisted in registers ONCE per block (wave owns 64 cols), W2 staged in LDS ONCE.
// hs A-frags prefetched one mt-tile ahead (HBM latency hidden under MFMA). LDS-only barriers.
__global__ __launch_bounds__(512, 2) void head_mfma4(
    const _Float16* __restrict__ hs,
    const _Float16* __restrict__ W1h, const float* __restrict__ b1,
    const _Float16* __restrict__ W2h, const float* __restrict__ b2,
    float* __restrict__ out)
{
    __shared__ __align__(16) _Float16 o1[64 * OSTRIDE];     // 66560 B
    __shared__ __align__(16) _Float16 w2s[64 * W2STRIDE];   // 66560 B (total 133 KB, 1 blk/CU)

    const int tid = threadIdx.x, wv = tid >> 6, lane = tid & 63;
    const int lrow = lane & 15, q = lane >> 4;

    // stage W2 (64x512) into padded LDS once
    for (int i = tid; i < OO * NHH; i += 512)
        w2s[(i >> 9) * W2STRIDE + (i & 511)] = W2h[i];

    // hoist W1 slice: wave owns cols [wv*64, +64)
    half8 B1[4][4];
    float bias1[4];
    #pragma unroll
    for (int nt = 0; nt < 4; ++nt) {
        bias1[nt] = b1[wv * 64 + nt * 16 + lrow];
        #pragma unroll
        for (int kt = 0; kt < 4; ++kt)
            B1[nt][kt] = *(const half8*)&W1h[(wv * 64 + nt * 16 + lrow) * HH + kt * 32 + q * 8];
    }
    const int mt2 = wv >> 1;          // GEMM2: 4 M-tiles x 2 N-pairs over 8 waves
    const int nh0 = (wv & 1) * 2;
    float bias2[2] = {b2[nh0 * 16 + lrow], b2[(nh0 + 1) * 16 + lrow]};

    const size_t row_base = (size_t)blockIdx.x * (32 * 64);

    // A prefetch for (tile 0, mt 0)
    half8 An[4];
    #pragma unroll
    for (int kt = 0; kt < 4; ++kt)
        An[kt] = *(const half8*)(hs + (row_base + lrow) * HH + kt * 32 + q * 8);

    __syncthreads();   // w2s ready

    for (int tile = 0; tile < 32; ++tile) {
        const size_t rows0 = row_base + (size_t)tile * 64;

        // GEMM1: 4 M-tiles, A streamed with 1-tile prefetch, B resident
        #pragma unroll
        for (int mt = 0; mt < 4; ++mt) {
            half8 Ac[4];
            #pragma unroll
            for (int kt = 0; kt < 4; ++kt) Ac[kt] = An[kt];
            if (!(tile == 31 && mt == 3)) {
                size_t nrow = rows0 + (size_t)(mt + 1) * 16;   // next mt / next tile's mt0
                #pragma unroll
                for (int kt = 0; kt < 4; ++kt)
                    An[kt] = *(const half8*)(hs + (nrow + lrow) * HH + kt * 32 + q * 8);
            }
            f32x4 C1[4];
            #pragma unroll
            for (int nt = 0; nt < 4; ++nt) {
                f32x4 ci = {bias1[nt], bias1[nt], bias1[nt], bias1[nt]};
                C1[nt] = ci;
            }
            #pragma unroll
            for (int kt = 0; kt < 4; ++kt)
                #pragma unroll
                for (int nt = 0; nt < 4; ++nt)
                    C1[nt] = __builtin_amdgcn_mfma_f32_16x16x32_f16(Ac[kt], B1[nt][kt], C1[nt], 0, 0, 0);
            #pragma unroll
            for (int nt = 0; nt < 4; ++nt)
                #pragma unroll
                for (int reg = 0; reg < 4; ++reg) {
                    float v = C1[nt][reg];
                    v = v > 0.f ? v : 0.f;
                    o1[(mt * 16 + q * 4 + reg) * OSTRIDE + wv * 64 + nt * 16 + lrow] = (_Float16)v;
                }
        }
        sync_lds();   // o1 complete

        // GEMM2: all operands in LDS
        f32x4 C2a[2], C2b[2];
        #pragma unroll
        for (int j = 0; j < 2; ++j) {
            f32x4 ci = {bias2[j], bias2[j], bias2[j], bias2[j]};
            C2a[j] = ci;
            f32x4 z = {0.f, 0.f, 0.f, 0.f};
            C2b[j] = z;
        }
        #pragma unroll
        for (int kt = 0; kt < 16; ++kt) {
            half8 ua = *(const half8*)&o1[(mt2 * 16 + lrow) * OSTRIDE + kt * 32 + q * 8];
            #pragma unroll
            for (int j = 0; j < 2; ++j) {
                half8 ub = *(const half8*)&w2s[((nh0 + j) * 16 + lrow) * W2STRIDE + kt * 32 + q * 8];
                if (kt & 1) C2b[j] = __builtin_amdgcn_mfma_f32_16x16x32_f16(ua, ub, C2b[j], 0, 0, 0);
                else        C2a[j] = __builtin_amdgcn_mfma_f32_16x16x32_f16(ua, ub, C2a[j], 0, 0, 0);
            }
        }
        #pragma unroll
        for (int j = 0; j < 2; ++j)
            #pragma unroll
            for (int reg = 0; reg < 4; ++reg)
                out[(rows0 + mt2 * 16 + q * 4 + reg) * OO + (nh0 + j) * 16 + lrow] = C2a[j][reg] + C2b[j][reg];
        sync_lds();   // o1 free for next tile
    }
}

extern "C" void kernel_launch(void* const* d_in, const int* in_sizes, int n_in,
                              void* d_out, int out_size, void* d_ws, size_t ws_size,
                              hipStream_t stream)
{
    const float* x    = (const float*)d_in[0];
    const float* W_ih = (const float*)d_in[1];
    const float* W_hh = (const float*)d_in[2];
    const float* b_ih = (const float*)d_in[3];
    const float* b_hh = (const float*)d_in[4];
    const float* W1   = (const float*)d_in[5];
    const float* b1   = (const float*)d_in[6];
    const float* W2   = (const float*)d_in[7];
    const float* b2   = (const float*)d_in[8];
    float* out = (float*)d_out;

    char* ws = (char*)d_ws;
    _Float16* W1h = (_Float16*)(ws + 0);             // 131072
    _Float16* W2h = (_Float16*)(ws + 131072);        // 65536
    _Float16* hs  = (_Float16*)(ws + 196608);        // 134217728 (f16 h history)

    prep_kernel<<<64, 256, 0, stream>>>(W1, W2, W1h, W2h);

    float* tail = out + (size_t)TT * BB * OO;
    lstm_scan10<<<BB, 512, 0, stream>>>(x, W_ih, W_hh, b_ih, b_hh, hs, tail);

    head_mfma4<<<BB, 512, 0, stream>>>(hs, W1h, b1, W2h, b2, out);
}